// Round 9
// baseline (149.401 us; speedup 1.0000x reference)
//
#include <hip/hip_runtime.h>
#include <math.h>

#define B_  4
#define C_  64
#define H_  128
#define W_  128
#define HW_ (H_*W_)          // 16384
#define NPIX_ (B_*HW_)       // 65536
#define GROUPS_ 32

typedef __attribute__((ext_vector_type(8))) short short8;
typedef __attribute__((ext_vector_type(4))) float f32x4;

__device__ inline short f2bf_rne(float f) {
    unsigned u = __float_as_uint(f);
    unsigned r = (u + 0x7FFFu + ((u >> 16) & 1u)) >> 16;
    return (short)r;
}
__device__ inline float bf2f(short h) {
    return __uint_as_float(((unsigned)(unsigned short)h) << 16);
}
__device__ inline short8 ld8(const short* p) {
    union { uint4 u; short8 s; } c;
    c.u = *(const uint4*)p;
    return c.s;
}

// ---------------------------------------------------------------------------
// K0: composite weight prep. off/mask = conv3x3(conv1x1(x)) is linear:
// Wcomp[cout][pos][ci] = sum_cm W2[cout][cm][pos] * W1[cm][ci].
// couts 0-17 = off, 18-26 = mask, 27-31 = zero. [32][9][64], bf16 hi/lo.
// ---------------------------------------------------------------------------
__global__ void k0_prep(const float* __restrict__ w_off1, const float* __restrict__ w_mask1,
                        const float* __restrict__ w_off2, const float* __restrict__ w_mask2,
                        short* __restrict__ wc_hi, short* __restrict__ wc_lo) {
    int i = blockIdx.x * 256 + threadIdx.x;     // 0..18431
    if (i >= 32 * 576) return;
    int cout = i / 576;
    int r    = i % 576;
    int pos  = r >> 6, ci = r & 63;
    float s = 0.f;
    if (cout < 18) {
        for (int cm = 0; cm < 64; cm++)
            s += w_off2[(cout * 64 + cm) * 9 + pos] * w_off1[cm * 64 + ci];
    } else if (cout < 27) {
        for (int cm = 0; cm < 64; cm++)
            s += w_mask2[((cout - 18) * 64 + cm) * 9 + pos] * w_mask1[cm * 64 + ci];
    }
    short h = f2bf_rne(s);
    wc_hi[i] = h;
    wc_lo[i] = f2bf_rne(s - bf2f(h));
}

// ---------------------------------------------------------------------------
// K1: NCHW fp32 -> NHWC bf16 transpose (xtb), MFMA-fragment write pattern.
// ---------------------------------------------------------------------------
__global__ __launch_bounds__(256) void k1_trans(const float* __restrict__ x,
                                                short* __restrict__ xtb) {
    int l   = threadIdx.x & 63;
    int wv  = threadIdx.x >> 6;
    int row = l >> 4, col = l & 15;
    int p0  = blockIdx.x * 64 + wv * 16;
    int b   = p0 >> 14;
    int hw  = p0 & (HW_ - 1);
    const float* xb = x + (size_t)b * C_ * HW_ + hw;
#pragma unroll
    for (int kb = 0; kb < 2; kb++) {
        int ci0 = kb * 32 + row * 8;
        float xv[8];
#pragma unroll
        for (int j = 0; j < 8; j++) xv[j] = xb[(ci0 + j) * HW_ + col];
        short8 a;
#pragma unroll
        for (int j = 0; j < 8; j++) a[j] = f2bf_rne(xv[j]);
        union { short8 s; uint4 u; } cv; cv.s = a;
        *(uint4*)(xtb + ((size_t)(p0 + col)) * 64 + ci0) = cv.u;
    }
}

// ---------------------------------------------------------------------------
// K2: fused off+mask 3x3x64 conv via MFMA on composite weights.
// K=576, N=32 (2 N-tiles), block = 4 waves x 32 px = one image row.
// Branch-free pipelined A loads. offmask[pix][32]: [0..17]=off, [18..26]=sig.
// ---------------------------------------------------------------------------
__global__ __launch_bounds__(256, 2) void k2_mfma(const short* __restrict__ xtb,
                                                  const short* __restrict__ wc_hi,
                                                  const short* __restrict__ wc_lo,
                                                  float* __restrict__ offmask) {
    int l   = threadIdx.x & 63;
    int wv  = threadIdx.x >> 6;
    int row = l >> 4, col = l & 15;
    int blk = blockIdx.x;
    int h   = blk & 127;
    int pb  = blk * 128 + wv * 32;            // wave's 32-px base
    int w0  = (pb & 127);

    const short8 zero = {0,0,0,0,0,0,0,0};
    f32x4 a00 = {0.f,0.f,0.f,0.f};
    f32x4 a01 = {0.f,0.f,0.f,0.f};
    f32x4 a10 = {0.f,0.f,0.f,0.f};
    f32x4 a11 = {0.f,0.f,0.f,0.f};

    short8 cw0, cw1, cw2, cw3, ca0, ca1;
    {
        const int pos = 0, dy = -1, dx = -1;
        int ci0 = row * 8;
        int ko  = pos * 64 + ci0;
        cw0 = ld8(wc_hi + (size_t)col * 576 + ko);
        cw1 = ld8(wc_lo + (size_t)col * 576 + ko);
        cw2 = ld8(wc_hi + (size_t)(col + 16) * 576 + ko);
        cw3 = ld8(wc_lo + (size_t)(col + 16) * 576 + ko);
#pragma unroll
        for (int mt = 0; mt < 2; mt++) {
            int pbase = pb + mt * 16 + col;
            int w = w0 + mt * 16 + col;
            bool valid = ((unsigned)(h + dy) < 128u) && ((unsigned)(w + dx) < 128u);
            int addr = valid ? (pbase + dy * 128 + dx) : pbase;
            short8 v = ld8(xtb + (size_t)addr * 64 + ci0);
            if (mt == 0) ca0 = valid ? v : zero; else ca1 = valid ? v : zero;
        }
    }

#pragma unroll
    for (int kb = 0; kb < 18; kb++) {
        short8 nw0, nw1, nw2, nw3, na0, na1;
        if (kb < 17) {
            const int kn = kb + 1;
            const int pos = kn >> 1;
            const int dy = pos / 3 - 1, dx = pos % 3 - 1;
            int ci0 = (kn & 1) * 32 + row * 8;
            int ko  = pos * 64 + ci0;
            nw0 = ld8(wc_hi + (size_t)col * 576 + ko);
            nw1 = ld8(wc_lo + (size_t)col * 576 + ko);
            nw2 = ld8(wc_hi + (size_t)(col + 16) * 576 + ko);
            nw3 = ld8(wc_lo + (size_t)(col + 16) * 576 + ko);
#pragma unroll
            for (int mt = 0; mt < 2; mt++) {
                int pbase = pb + mt * 16 + col;
                int w = w0 + mt * 16 + col;
                bool valid = ((unsigned)(h + dy) < 128u) && ((unsigned)(w + dx) < 128u);
                int addr = valid ? (pbase + dy * 128 + dx) : pbase;
                short8 v = ld8(xtb + (size_t)addr * 64 + ci0);
                if (mt == 0) na0 = valid ? v : zero; else na1 = valid ? v : zero;
            }
        }
        a00 = __builtin_amdgcn_mfma_f32_16x16x32_bf16(ca0, cw0, a00, 0, 0, 0);
        a00 = __builtin_amdgcn_mfma_f32_16x16x32_bf16(ca0, cw1, a00, 0, 0, 0);
        a01 = __builtin_amdgcn_mfma_f32_16x16x32_bf16(ca0, cw2, a01, 0, 0, 0);
        a01 = __builtin_amdgcn_mfma_f32_16x16x32_bf16(ca0, cw3, a01, 0, 0, 0);
        a10 = __builtin_amdgcn_mfma_f32_16x16x32_bf16(ca1, cw0, a10, 0, 0, 0);
        a10 = __builtin_amdgcn_mfma_f32_16x16x32_bf16(ca1, cw1, a10, 0, 0, 0);
        a11 = __builtin_amdgcn_mfma_f32_16x16x32_bf16(ca1, cw2, a11, 0, 0, 0);
        a11 = __builtin_amdgcn_mfma_f32_16x16x32_bf16(ca1, cw3, a11, 0, 0, 0);
        cw0 = nw0; cw1 = nw1; cw2 = nw2; cw3 = nw3;
        ca0 = na0; ca1 = na1;
    }

#pragma unroll
    for (int mt = 0; mt < 2; mt++) {
        f32x4 n0 = mt ? a10 : a00;
        f32x4 n1 = mt ? a11 : a01;
#pragma unroll
        for (int r = 0; r < 4; r++) {
            int p = pb + mt * 16 + row * 4 + r;
            float* om = offmask + (size_t)p * 32;
            om[col] = n0[r];
            if (col < 2)       om[16 + col] = n1[r];
            else if (col < 11) om[16 + col] = 1.f / (1.f + expf(-n1[r]));
        }
    }
}

// ---------------------------------------------------------------------------
// K3: deformable bilinear gather + einsum + bias -> out_pre (NCHW, bf16)
// + per-block GroupNorm partials. 8 threads/pixel x 8 channels (one 16B load
// per corner) -> 2048 blocks x 4 waves = 8192 waves = full occupancy.
// XCD-band swizzle: block i -> XCD i&7; XCD x owns rows [16x,16x+16).
// ---------------------------------------------------------------------------
__global__ __launch_bounds__(256) void k3_deform(const short* __restrict__ xtb,
                                                 const float* __restrict__ offmask,
                                                 const float* __restrict__ weight,
                                                 const float* __restrict__ bias,
                                                 unsigned short* __restrict__ out_pre,
                                                 float* __restrict__ partials) {
    __shared__ float wl[C_ * 9];
    __shared__ float bl[C_];
    __shared__ float lds_s[4][8][4];
    __shared__ float lds_ss[4][8][4];
    for (int i = threadIdx.x; i < C_ * 9; i += 256) wl[i] = weight[i];
    if (threadIdx.x < C_) bl[threadIdx.x] = bias[threadIdx.x];
    __syncthreads();

    int blk   = blockIdx.x;              // 2048 blocks, 32 pixels each
    int xcd   = blk & 7;
    int s_    = blk >> 3;                // 0..255
    int b     = s_ >> 6;                 // image
    int t     = s_ & 63;                 // slot within (image, xcd band)
    int r     = t >> 2;                  // row within band (0..15)
    int q     = t & 3;                   // quarter-row
    int h     = xcd * 16 + r;
    int pl    = threadIdx.x >> 3;        // 0..31 pixel within block
    int chunk = threadIdx.x & 7;
    int c0    = chunk * 8;
    int w     = q * 32 + pl;
    int hw    = h * W_ + w;
    int P     = b * HW_ + hw;
    int slot_img = xcd * 64 + t;         // 0..511 within image

    float acc[8];
#pragma unroll
    for (int i = 0; i < 8; i++) acc[i] = 0.f;

    const float* po = offmask + (size_t)P * 32;
    const short* xb = xtb + (size_t)b * HW_ * 64;

    for (int k = 0; k < 9; k++) {
        float offy = po[2 * k];
        float offx = po[2 * k + 1];
        float mk   = po[18 + k];
        float py = offy + (float)h + (float)(k / 3 - 1);
        float px = offx + (float)w + (float)(k % 3 - 1);
        float y0f = floorf(py), x0f = floorf(px);
        int y0 = (int)y0f, x0 = (int)x0f;
        int y1 = y0 + 1,   x1 = x0 + 1;
        float wy1 = py - y0f, wx1 = px - x0f;
        float wy0 = 1.f - wy1, wx0 = 1.f - wx1;
        bool vy0 = ((unsigned)y0 < (unsigned)H_);
        bool vy1 = ((unsigned)y1 < (unsigned)H_);
        bool vx0 = ((unsigned)x0 < (unsigned)W_);
        bool vx1 = ((unsigned)x1 < (unsigned)W_);
        int cy0 = min(max(y0, 0), H_ - 1);
        int cy1 = min(max(y1, 0), H_ - 1);
        int cx0 = min(max(x0, 0), W_ - 1);
        int cx1 = min(max(x1, 0), W_ - 1);
        float b00 = wy0 * wx0 * ((vy0 && vx0) ? mk : 0.f);
        float b01 = wy0 * wx1 * ((vy0 && vx1) ? mk : 0.f);
        float b10 = wy1 * wx0 * ((vy1 && vx0) ? mk : 0.f);
        float b11 = wy1 * wx1 * ((vy1 && vx1) ? mk : 0.f);

        uint4 u00 = *(const uint4*)(xb + ((size_t)cy0 * W_ + cx0) * 64 + c0);
        uint4 u01 = *(const uint4*)(xb + ((size_t)cy0 * W_ + cx1) * 64 + c0);
        uint4 u10 = *(const uint4*)(xb + ((size_t)cy1 * W_ + cx0) * 64 + c0);
        uint4 u11 = *(const uint4*)(xb + ((size_t)cy1 * W_ + cx1) * 64 + c0);
        unsigned a00[4] = {u00.x, u00.y, u00.z, u00.w};
        unsigned a01[4] = {u01.x, u01.y, u01.z, u01.w};
        unsigned a10[4] = {u10.x, u10.y, u10.z, u10.w};
        unsigned a11[4] = {u11.x, u11.y, u11.z, u11.w};
#pragma unroll
        for (int d = 0; d < 4; d++) {
            float s_lo = b00 * __uint_as_float(a00[d] << 16)
                       + b01 * __uint_as_float(a01[d] << 16)
                       + b10 * __uint_as_float(a10[d] << 16)
                       + b11 * __uint_as_float(a11[d] << 16);
            float s_hi = b00 * __uint_as_float(a00[d] & 0xFFFF0000u)
                       + b01 * __uint_as_float(a01[d] & 0xFFFF0000u)
                       + b10 * __uint_as_float(a10[d] & 0xFFFF0000u)
                       + b11 * __uint_as_float(a11[d] & 0xFFFF0000u);
            int c = 2 * d;
            acc[c]     += wl[(c0 + c) * 9 + k] * s_lo;
            acc[c + 1] += wl[(c0 + c + 1) * 9 + k] * s_hi;
        }
    }

    // bias + bf16 store
    unsigned short* op = out_pre + ((size_t)b * C_ + c0) * HW_ + hw;
#pragma unroll
    for (int c = 0; c < 8; c++) {
        acc[c] += bl[c0 + c];
        op[c * HW_] = (unsigned short)f2bf_rne(acc[c]);
    }

    // GroupNorm partials: this thread's groups = c0/2 + j, j=0..3
    float s4[4], ss4[4];
#pragma unroll
    for (int j = 0; j < 4; j++) {
        float a0 = acc[2 * j], a1 = acc[2 * j + 1];
        s4[j]  = a0 + a1;
        ss4[j] = a0 * a0 + a1 * a1;
    }
    // reduce over the 8 pixels of this wave (lane = px*8 + chunk)
#pragma unroll
    for (int m = 8; m < 64; m <<= 1) {
#pragma unroll
        for (int j = 0; j < 4; j++) {
            s4[j]  += __shfl_xor(s4[j], m);
            ss4[j] += __shfl_xor(ss4[j], m);
        }
    }
    int lane = threadIdx.x & 63, wid = threadIdx.x >> 6;
    if (lane < 8) {
#pragma unroll
        for (int j = 0; j < 4; j++) {
            lds_s[wid][lane][j]  = s4[j];
            lds_ss[wid][lane][j] = ss4[j];
        }
    }
    __syncthreads();
    if (threadIdx.x < 32) {
        int g = threadIdx.x;                 // group 0..31
        int ch = g >> 2, j = g & 3;          // chunk, pair
        float S  = lds_s[0][ch][j] + lds_s[1][ch][j] + lds_s[2][ch][j] + lds_s[3][ch][j];
        float SS = lds_ss[0][ch][j] + lds_ss[1][ch][j] + lds_ss[2][ch][j] + lds_ss[3][ch][j];
        float2 v = make_float2(S, SS);
        *(float2*)(partials + (((size_t)(b * GROUPS_ + g)) * 512 + slot_img) * 2) = v;
    }
}

// ---------------------------------------------------------------------------
// K4: reduce partials -> stats. 128 blocks (one per b*32+g), 256 threads,
// 512 slots each (2 per thread).
// ---------------------------------------------------------------------------
__global__ __launch_bounds__(256) void k4_reduce(const float* __restrict__ partials,
                                                 float* __restrict__ stats) {
    int bg = blockIdx.x;
    const float2* p = (const float2*)partials + (size_t)bg * 512;
    float2 v0 = p[threadIdx.x];
    float2 v1 = p[threadIdx.x + 256];
    float s = v0.x + v1.x, ss = v0.y + v1.y;
#pragma unroll
    for (int m = 1; m < 64; m <<= 1) {
        s  += __shfl_xor(s, m);
        ss += __shfl_xor(ss, m);
    }
    __shared__ float ls[8];
    int lane = threadIdx.x & 63, wid = threadIdx.x >> 6;
    if (lane == 0) { ls[wid] = s; ls[4 + wid] = ss; }
    __syncthreads();
    if (threadIdx.x == 0) {
        float S  = ls[0] + ls[1] + ls[2] + ls[3];
        float SS = ls[4] + ls[5] + ls[6] + ls[7];
        const float inv = 1.f / (2.f * HW_);
        float mean = S * inv;
        float var  = SS * inv - mean * mean;
        stats[bg * 2]     = mean;
        stats[bg * 2 + 1] = rsqrtf(var + 1e-5f);
    }
}

// ---------------------------------------------------------------------------
// K5: normalize + gamma/beta + exact GELU. Reads bf16 out_pre (8/thread),
// writes fp32 d_out.
// ---------------------------------------------------------------------------
__global__ __launch_bounds__(256) void k5_norm_gelu(const unsigned short* __restrict__ out_pre,
                                                    const float* __restrict__ stats,
                                                    const float* __restrict__ gamma,
                                                    const float* __restrict__ beta,
                                                    float* __restrict__ out) {
    int i = blockIdx.x * 256 + threadIdx.x;       // 8-element index
    int e = i << 3;
    int c = (e >> 14) & (C_ - 1);
    int b = e >> 20;
    int bg = b * GROUPS_ + (c >> 1);
    float mean = stats[bg * 2];
    float rstd = stats[bg * 2 + 1];
    float ga = gamma[c] * rstd;
    float be = beta[c] - mean * ga;
    uint4 v = ((const uint4*)out_pre)[i];
    unsigned dw[4] = {v.x, v.y, v.z, v.w};
    float o[8];
#pragma unroll
    for (int d = 0; d < 4; d++) {
        float lo = __uint_as_float(dw[d] << 16);
        float hi = __uint_as_float(dw[d] & 0xFFFF0000u);
        float t0 = lo * ga + be;
        float t1 = hi * ga + be;
        o[2 * d]     = 0.5f * t0 * (1.f + erff(t0 * 0.70710678118654752f));
        o[2 * d + 1] = 0.5f * t1 * (1.f + erff(t1 * 0.70710678118654752f));
    }
    ((float4*)out)[2 * i]     = make_float4(o[0], o[1], o[2], o[3]);
    ((float4*)out)[2 * i + 1] = make_float4(o[4], o[5], o[6], o[7]);
}

// ---------------------------------------------------------------------------
extern "C" void kernel_launch(void* const* d_in, const int* in_sizes, int n_in,
                              void* d_out, int out_size, void* d_ws, size_t ws_size,
                              hipStream_t stream) {
    const float* x       = (const float*)d_in[0];
    const float* w_off1  = (const float*)d_in[1];
    const float* w_off2  = (const float*)d_in[2];
    const float* w_mask1 = (const float*)d_in[3];
    const float* w_mask2 = (const float*)d_in[4];
    const float* weight  = (const float*)d_in[5];
    const float* bias    = (const float*)d_in[6];
    const float* gamma   = (const float*)d_in[7];
    const float* beta    = (const float*)d_in[8];
    float* out = (float*)d_out;

    char* ws = (char*)d_ws;
    size_t o = 0;
    short* wc_hi = (short*)(ws + o); o += 32 * 576 * 2;
    short* wc_lo = (short*)(ws + o); o += 32 * 576 * 2;
    o = (o + 255) & ~(size_t)255;
    short* xtb               = (short*)(ws + o);          o += (size_t)NPIX_ * 64 * 2;
    float* offmask           = (float*)(ws + o);          o += (size_t)NPIX_ * 32 * 4;
    unsigned short* out_pre  = (unsigned short*)(ws + o); o += (size_t)NPIX_ * 64 * 2;
    float* partials          = (float*)(ws + o);          o += (size_t)128 * 512 * 2 * 4;
    float* stats             = (float*)(ws + o);          o += 256 * 4;

    hipLaunchKernelGGL(k0_prep, dim3(72), dim3(256), 0, stream,
                       w_off1, w_mask1, w_off2, w_mask2, wc_hi, wc_lo);
    hipLaunchKernelGGL(k1_trans, dim3(NPIX_ / 64), dim3(256), 0, stream,
                       x, xtb);
    hipLaunchKernelGGL(k2_mfma, dim3(NPIX_ / 128), dim3(256), 0, stream,
                       xtb, wc_hi, wc_lo, offmask);
    hipLaunchKernelGGL(k3_deform, dim3(NPIX_ / 32), dim3(256), 0, stream,
                       xtb, offmask, weight, bias, out_pre, partials);
    hipLaunchKernelGGL(k4_reduce, dim3(B_ * GROUPS_), dim3(256), 0, stream,
                       partials, stats);
    hipLaunchKernelGGL(k5_norm_gelu, dim3(NPIX_ * 64 / 8 / 256), dim3(256), 0, stream,
                       out_pre, stats, gamma, beta, out);
}

// Round 10
// 135.969 us; speedup vs baseline: 1.0988x; 1.0988x over previous
//
#include <hip/hip_runtime.h>
#include <math.h>

#define B_  4
#define C_  64
#define H_  128
#define W_  128
#define HW_ (H_*W_)          // 16384
#define NPIX_ (B_*HW_)       // 65536
#define GROUPS_ 32

typedef __attribute__((ext_vector_type(8))) short short8;
typedef __attribute__((ext_vector_type(4))) float f32x4;

__device__ inline short f2bf_rne(float f) {
    unsigned u = __float_as_uint(f);
    unsigned r = (u + 0x7FFFu + ((u >> 16) & 1u)) >> 16;
    return (short)r;
}
__device__ inline short8 ld8(const short* p) {
    union { uint4 u; short8 s; } c;
    c.u = *(const uint4*)p;
    return c.s;
}

// ---------------------------------------------------------------------------
// K01: blocks [0,1024): NCHW fp32 -> NHWC bf16 transpose (xtb).
//      blocks [1024,1096): composite weight prep (hi only):
//      Wcomp[cout][pos][ci] = sum_cm W2[cout][cm][pos] * W1[cm][ci], bf16.
//      couts 0-17 = off, 18-26 = mask, 27-31 = zero. Layout [32][9][64].
// ---------------------------------------------------------------------------
__global__ __launch_bounds__(256) void k01(const float* __restrict__ x,
                                           const float* __restrict__ w_off1,
                                           const float* __restrict__ w_mask1,
                                           const float* __restrict__ w_off2,
                                           const float* __restrict__ w_mask2,
                                           short* __restrict__ xtb,
                                           short* __restrict__ wc_hi) {
    if (blockIdx.x >= 1024) {
        int i = (blockIdx.x - 1024) * 256 + threadIdx.x;   // 0..18431
        if (i < 32 * 576) {
            int cout = i / 576;
            int r    = i % 576;
            int pos  = r >> 6, ci = r & 63;
            float s = 0.f;
            if (cout < 18) {
                for (int cm = 0; cm < 64; cm++)
                    s += w_off2[(cout * 64 + cm) * 9 + pos] * w_off1[cm * 64 + ci];
            } else if (cout < 27) {
                for (int cm = 0; cm < 64; cm++)
                    s += w_mask2[((cout - 18) * 64 + cm) * 9 + pos] * w_mask1[cm * 64 + ci];
            }
            wc_hi[i] = f2bf_rne(s);
        }
        return;
    }
    int l   = threadIdx.x & 63;
    int wv  = threadIdx.x >> 6;
    int row = l >> 4, col = l & 15;
    int p0  = blockIdx.x * 64 + wv * 16;
    int b   = p0 >> 14;
    int hw  = p0 & (HW_ - 1);
    const float* xb = x + (size_t)b * C_ * HW_ + hw;
#pragma unroll
    for (int kb = 0; kb < 2; kb++) {
        int ci0 = kb * 32 + row * 8;
        float xv[8];
#pragma unroll
        for (int j = 0; j < 8; j++) xv[j] = xb[(ci0 + j) * HW_ + col];
        short8 a;
#pragma unroll
        for (int j = 0; j < 8; j++) a[j] = f2bf_rne(xv[j]);
        union { short8 s; uint4 u; } cv; cv.s = a;
        *(uint4*)(xtb + ((size_t)(p0 + col)) * 64 + ci0) = cv.u;
    }
}

// ---------------------------------------------------------------------------
// K2: fused off+mask 3x3x64 conv via MFMA on composite weights (hi only).
// K=576, N=32 (2 N-tiles), block = 4 waves x 32 px = one image row.
// ALL 36 weight fragments preloaded into registers before the K-loop
// (loop-invariant addresses; 144 VGPR); loop = 4 MFMA + 2 pipelined A-loads.
// offmask[pix][32]: [0..17]=off, [18..26]=sigmoid(mask).
// ---------------------------------------------------------------------------
__global__ __launch_bounds__(256, 2) void k2_mfma(const short* __restrict__ xtb,
                                                  const short* __restrict__ wc_hi,
                                                  float* __restrict__ offmask) {
    int l   = threadIdx.x & 63;
    int wv  = threadIdx.x >> 6;
    int row = l >> 4, col = l & 15;
    int blk = blockIdx.x;
    int h   = blk & 127;
    int pb  = blk * 128 + wv * 32;            // wave's 32-px base
    int w0  = (pb & 127);

    // Preload all weight fragments (hi only): wfr[kb][ntile]
    short8 wfr[18][2];
#pragma unroll
    for (int kb = 0; kb < 18; kb++) {
        int pos = kb >> 1;
        int ci0 = (kb & 1) * 32 + row * 8;
        int ko  = pos * 64 + ci0;
        wfr[kb][0] = ld8(wc_hi + (size_t)col * 576 + ko);
        wfr[kb][1] = ld8(wc_hi + (size_t)(col + 16) * 576 + ko);
    }

    const short8 zero = {0,0,0,0,0,0,0,0};
    f32x4 a00 = {0.f,0.f,0.f,0.f};
    f32x4 a01 = {0.f,0.f,0.f,0.f};
    f32x4 a10 = {0.f,0.f,0.f,0.f};
    f32x4 a11 = {0.f,0.f,0.f,0.f};

    short8 ca0, ca1;
    {
        const int dy = -1, dx = -1;          // kb=0: pos=0
        int ci0 = row * 8;
#pragma unroll
        for (int mt = 0; mt < 2; mt++) {
            int pbase = pb + mt * 16 + col;
            int w = w0 + mt * 16 + col;
            bool valid = ((unsigned)(h + dy) < 128u) && ((unsigned)(w + dx) < 128u);
            int addr = valid ? (pbase + dy * 128 + dx) : pbase;
            short8 v = ld8(xtb + (size_t)addr * 64 + ci0);
            if (mt == 0) ca0 = valid ? v : zero; else ca1 = valid ? v : zero;
        }
    }

#pragma unroll
    for (int kb = 0; kb < 18; kb++) {
        short8 na0, na1;
        if (kb < 17) {
            const int kn = kb + 1;
            const int pos = kn >> 1;
            const int dy = pos / 3 - 1, dx = pos % 3 - 1;
            int ci0 = (kn & 1) * 32 + row * 8;
#pragma unroll
            for (int mt = 0; mt < 2; mt++) {
                int pbase = pb + mt * 16 + col;
                int w = w0 + mt * 16 + col;
                bool valid = ((unsigned)(h + dy) < 128u) && ((unsigned)(w + dx) < 128u);
                int addr = valid ? (pbase + dy * 128 + dx) : pbase;
                short8 v = ld8(xtb + (size_t)addr * 64 + ci0);
                if (mt == 0) na0 = valid ? v : zero; else na1 = valid ? v : zero;
            }
        }
        a00 = __builtin_amdgcn_mfma_f32_16x16x32_bf16(ca0, wfr[kb][0], a00, 0, 0, 0);
        a01 = __builtin_amdgcn_mfma_f32_16x16x32_bf16(ca0, wfr[kb][1], a01, 0, 0, 0);
        a10 = __builtin_amdgcn_mfma_f32_16x16x32_bf16(ca1, wfr[kb][0], a10, 0, 0, 0);
        a11 = __builtin_amdgcn_mfma_f32_16x16x32_bf16(ca1, wfr[kb][1], a11, 0, 0, 0);
        ca0 = na0; ca1 = na1;
    }

#pragma unroll
    for (int mt = 0; mt < 2; mt++) {
        f32x4 n0 = mt ? a10 : a00;
        f32x4 n1 = mt ? a11 : a01;
#pragma unroll
        for (int r = 0; r < 4; r++) {
            int p = pb + mt * 16 + row * 4 + r;
            float* om = offmask + (size_t)p * 32;
            om[col] = n0[r];
            if (col < 2)       om[16 + col] = n1[r];
            else if (col < 11) om[16 + col] = 1.f / (1.f + expf(-n1[r]));
        }
    }
}

// ---------------------------------------------------------------------------
// K3: deformable bilinear gather + einsum + bias -> out_pre (NCHW, bf16)
// + per-block GroupNorm partials. 4 thr/px x 16 ch, 1024 blocks x 64 px.
// XCD-band swizzle: block i -> XCD i&7; XCD x owns rows [16x,16x+16).
// ---------------------------------------------------------------------------
__global__ __launch_bounds__(256) void k3_deform(const short* __restrict__ xtb,
                                                 const float* __restrict__ offmask,
                                                 const float* __restrict__ weight,
                                                 const float* __restrict__ bias,
                                                 unsigned short* __restrict__ out_pre,
                                                 float* __restrict__ partials) {
    __shared__ float wl[C_ * 9];
    __shared__ float bl[C_];
    __shared__ float lds_s[4][4][8];
    __shared__ float lds_ss[4][4][8];
    for (int i = threadIdx.x; i < C_ * 9; i += 256) wl[i] = weight[i];
    if (threadIdx.x < C_) bl[threadIdx.x] = bias[threadIdx.x];
    __syncthreads();

    int blk   = blockIdx.x;              // 1024 blocks, 64 pixels each
    int xcd   = blk & 7;
    int slot  = blk >> 3;                // 0..127
    int b     = slot >> 5;               // image
    int r     = (slot & 31) >> 1;        // row within band
    int hrow  = slot & 1;                // half-row
    int h     = xcd * 16 + r;
    int pl    = threadIdx.x >> 2;        // 0..63
    int chunk = threadIdx.x & 3;
    int c0    = chunk * 16;
    int w     = hrow * 64 + pl;
    int hw    = h * W_ + w;
    int P     = b * HW_ + hw;
    int slot_img = xcd * 32 + (slot & 31);   // 0..255 within image

    float acc[16];
#pragma unroll
    for (int i = 0; i < 16; i++) acc[i] = 0.f;

    const float* po = offmask + (size_t)P * 32;
    const short* xb = xtb + (size_t)b * HW_ * 64;

    for (int k = 0; k < 9; k++) {
        float offy = po[2 * k];
        float offx = po[2 * k + 1];
        float mk   = po[18 + k];
        float py = offy + (float)h + (float)(k / 3 - 1);
        float px = offx + (float)w + (float)(k % 3 - 1);
        float y0f = floorf(py), x0f = floorf(px);
        int y0 = (int)y0f, x0 = (int)x0f;
        int y1 = y0 + 1,   x1 = x0 + 1;
        float wy1 = py - y0f, wx1 = px - x0f;
        float wy0 = 1.f - wy1, wx0 = 1.f - wx1;
        bool vy0 = ((unsigned)y0 < (unsigned)H_);
        bool vy1 = ((unsigned)y1 < (unsigned)H_);
        bool vx0 = ((unsigned)x0 < (unsigned)W_);
        bool vx1 = ((unsigned)x1 < (unsigned)W_);
        int cy0 = min(max(y0, 0), H_ - 1);
        int cy1 = min(max(y1, 0), H_ - 1);
        int cx0 = min(max(x0, 0), W_ - 1);
        int cx1 = min(max(x1, 0), W_ - 1);
        float b00 = wy0 * wx0 * ((vy0 && vx0) ? mk : 0.f);
        float b01 = wy0 * wx1 * ((vy0 && vx1) ? mk : 0.f);
        float b10 = wy1 * wx0 * ((vy1 && vx0) ? mk : 0.f);
        float b11 = wy1 * wx1 * ((vy1 && vx1) ? mk : 0.f);

        const short* p00 = xb + ((size_t)cy0 * W_ + cx0) * 64 + c0;
        const short* p01 = xb + ((size_t)cy0 * W_ + cx1) * 64 + c0;
        const short* p10 = xb + ((size_t)cy1 * W_ + cx0) * 64 + c0;
        const short* p11 = xb + ((size_t)cy1 * W_ + cx1) * 64 + c0;

#pragma unroll
        for (int half = 0; half < 2; half++) {
            uint4 u00 = *(const uint4*)(p00 + 8 * half);
            uint4 u01 = *(const uint4*)(p01 + 8 * half);
            uint4 u10 = *(const uint4*)(p10 + 8 * half);
            uint4 u11 = *(const uint4*)(p11 + 8 * half);
            unsigned a00[4] = {u00.x, u00.y, u00.z, u00.w};
            unsigned a01[4] = {u01.x, u01.y, u01.z, u01.w};
            unsigned a10[4] = {u10.x, u10.y, u10.z, u10.w};
            unsigned a11[4] = {u11.x, u11.y, u11.z, u11.w};
#pragma unroll
            for (int d = 0; d < 4; d++) {
                float s_lo = b00 * __uint_as_float(a00[d] << 16)
                           + b01 * __uint_as_float(a01[d] << 16)
                           + b10 * __uint_as_float(a10[d] << 16)
                           + b11 * __uint_as_float(a11[d] << 16);
                float s_hi = b00 * __uint_as_float(a00[d] & 0xFFFF0000u)
                           + b01 * __uint_as_float(a01[d] & 0xFFFF0000u)
                           + b10 * __uint_as_float(a10[d] & 0xFFFF0000u)
                           + b11 * __uint_as_float(a11[d] & 0xFFFF0000u);
                int c = 8 * half + 2 * d;
                acc[c]     += wl[(c0 + c) * 9 + k] * s_lo;
                acc[c + 1] += wl[(c0 + c + 1) * 9 + k] * s_hi;
            }
        }
    }

    // bias + bf16 store
    unsigned short* op = out_pre + ((size_t)b * C_ + c0) * HW_ + hw;
#pragma unroll
    for (int c = 0; c < 16; c++) {
        acc[c] += bl[c0 + c];
        op[c * HW_] = (unsigned short)f2bf_rne(acc[c]);
    }

    // GroupNorm partials: groups for this thread = chunk*8 + j, j=0..7
    float s8[8], ss8[8];
#pragma unroll
    for (int j = 0; j < 8; j++) {
        float a0 = acc[2 * j], a1 = acc[2 * j + 1];
        s8[j]  = a0 + a1;
        ss8[j] = a0 * a0 + a1 * a1;
    }
#pragma unroll
    for (int m = 4; m < 64; m <<= 1) {
#pragma unroll
        for (int j = 0; j < 8; j++) {
            s8[j]  += __shfl_xor(s8[j], m);
            ss8[j] += __shfl_xor(ss8[j], m);
        }
    }
    int lane = threadIdx.x & 63, wid = threadIdx.x >> 6;
    if (lane < 4) {
#pragma unroll
        for (int j = 0; j < 8; j++) {
            lds_s[wid][lane][j]  = s8[j];
            lds_ss[wid][lane][j] = ss8[j];
        }
    }
    __syncthreads();
    if (threadIdx.x < 32) {
        int g = threadIdx.x;
        int ch = g >> 3, j = g & 7;
        float S  = lds_s[0][ch][j] + lds_s[1][ch][j] + lds_s[2][ch][j] + lds_s[3][ch][j];
        float SS = lds_ss[0][ch][j] + lds_ss[1][ch][j] + lds_ss[2][ch][j] + lds_ss[3][ch][j];
        float2 v = make_float2(S, SS);
        *(float2*)(partials + (((size_t)(b * GROUPS_ + g)) * 256 + slot_img) * 2) = v;
    }
}

// ---------------------------------------------------------------------------
// K4: reduce partials -> stats. 128 blocks (one per b*32+g), 256 threads.
// ---------------------------------------------------------------------------
__global__ __launch_bounds__(256) void k4_reduce(const float* __restrict__ partials,
                                                 float* __restrict__ stats) {
    int bg = blockIdx.x;
    float2 v = ((const float2*)partials)[bg * 256 + threadIdx.x];
    float s = v.x, ss = v.y;
#pragma unroll
    for (int m = 1; m < 64; m <<= 1) {
        s  += __shfl_xor(s, m);
        ss += __shfl_xor(ss, m);
    }
    __shared__ float ls[8];
    int lane = threadIdx.x & 63, wid = threadIdx.x >> 6;
    if (lane == 0) { ls[wid] = s; ls[4 + wid] = ss; }
    __syncthreads();
    if (threadIdx.x == 0) {
        float S  = ls[0] + ls[1] + ls[2] + ls[3];
        float SS = ls[4] + ls[5] + ls[6] + ls[7];
        const float inv = 1.f / (2.f * HW_);
        float mean = S * inv;
        float var  = SS * inv - mean * mean;
        stats[bg * 2]     = mean;
        stats[bg * 2 + 1] = rsqrtf(var + 1e-5f);
    }
}

// ---------------------------------------------------------------------------
// K5: normalize + gamma/beta + exact GELU. Reads bf16 out_pre (8/thread),
// writes fp32 d_out.
// ---------------------------------------------------------------------------
__global__ __launch_bounds__(256) void k5_norm_gelu(const unsigned short* __restrict__ out_pre,
                                                    const float* __restrict__ stats,
                                                    const float* __restrict__ gamma,
                                                    const float* __restrict__ beta,
                                                    float* __restrict__ out) {
    int i = blockIdx.x * 256 + threadIdx.x;       // 8-element index
    int e = i << 3;
    int c = (e >> 14) & (C_ - 1);
    int b = e >> 20;
    int bg = b * GROUPS_ + (c >> 1);
    float mean = stats[bg * 2];
    float rstd = stats[bg * 2 + 1];
    float ga = gamma[c] * rstd;
    float be = beta[c] - mean * ga;
    uint4 v = ((const uint4*)out_pre)[i];
    unsigned dw[4] = {v.x, v.y, v.z, v.w};
    float o[8];
#pragma unroll
    for (int d = 0; d < 4; d++) {
        float lo = __uint_as_float(dw[d] << 16);
        float hi = __uint_as_float(dw[d] & 0xFFFF0000u);
        float t0 = lo * ga + be;
        float t1 = hi * ga + be;
        o[2 * d]     = 0.5f * t0 * (1.f + erff(t0 * 0.70710678118654752f));
        o[2 * d + 1] = 0.5f * t1 * (1.f + erff(t1 * 0.70710678118654752f));
    }
    ((float4*)out)[2 * i]     = make_float4(o[0], o[1], o[2], o[3]);
    ((float4*)out)[2 * i + 1] = make_float4(o[4], o[5], o[6], o[7]);
}

// ---------------------------------------------------------------------------
extern "C" void kernel_launch(void* const* d_in, const int* in_sizes, int n_in,
                              void* d_out, int out_size, void* d_ws, size_t ws_size,
                              hipStream_t stream) {
    const float* x       = (const float*)d_in[0];
    const float* w_off1  = (const float*)d_in[1];
    const float* w_off2  = (const float*)d_in[2];
    const float* w_mask1 = (const float*)d_in[3];
    const float* w_mask2 = (const float*)d_in[4];
    const float* weight  = (const float*)d_in[5];
    const float* bias    = (const float*)d_in[6];
    const float* gamma   = (const float*)d_in[7];
    const float* beta    = (const float*)d_in[8];
    float* out = (float*)d_out;

    char* ws = (char*)d_ws;
    size_t o = 0;
    short* wc_hi = (short*)(ws + o); o += 32 * 576 * 2;
    o = (o + 255) & ~(size_t)255;
    short* xtb               = (short*)(ws + o);          o += (size_t)NPIX_ * 64 * 2;
    float* offmask           = (float*)(ws + o);          o += (size_t)NPIX_ * 32 * 4;
    unsigned short* out_pre  = (unsigned short*)(ws + o); o += (size_t)NPIX_ * 64 * 2;
    float* partials          = (float*)(ws + o);          o += (size_t)128 * 256 * 2 * 4;
    float* stats             = (float*)(ws + o);          o += 256 * 4;

    hipLaunchKernelGGL(k01, dim3(1024 + 72), dim3(256), 0, stream,
                       x, w_off1, w_mask1, w_off2, w_mask2, xtb, wc_hi);
    hipLaunchKernelGGL(k2_mfma, dim3(NPIX_ / 128), dim3(256), 0, stream,
                       xtb, wc_hi, offmask);
    hipLaunchKernelGGL(k3_deform, dim3(NPIX_ / 64), dim3(256), 0, stream,
                       xtb, offmask, weight, bias, out_pre, partials);
    hipLaunchKernelGGL(k4_reduce, dim3(B_ * GROUPS_), dim3(256), 0, stream,
                       partials, stats);
    hipLaunchKernelGGL(k5_norm_gelu, dim3(NPIX_ * 64 / 8 / 256), dim3(256), 0, stream,
                       out_pre, stats, gamma, beta, out);
}